// Round 17
// baseline (61.194 us; speedup 1.0000x reference)
//
#include <hip/hip_runtime.h>
#include <stdint.h>

#define KCODES  1024
#define CDIM    64
#define SPATIAL 32768
#define NPOS    65536
#define NEL     4194304

// d_out layout (floats), outputs concatenated in reference return order
#define OUT_Q    0
#define OUT_LOSS 4194304
#define OUT_IDX  4194305
#define OUT_SUM  4259841
#define OUT_EMB  4260097

// ws: 64 sets x 4KB {Ah0(ch0-31),Ah1(ch32-63),Al0,Al1} 1KB chunks (lane-linear
// 16x16x32 A-frags, 16 codes/set), then eiE[1024] f32 (-0.5||e||^2) at EIOFF
#define SETB   4096
#define EIOFF  262144
#define BPOS   32
#define NRND   32          // rounds per wave (K-split 2: 32 sets of 16 codes)

typedef _Float16 half8 __attribute__((ext_vector_type(8)));
typedef float    f32x4 __attribute__((ext_vector_type(4)));

// ---- prep: fragment-swizzle codebook into 16-code sets, ei, zero, passthrough ----
__global__ void prep_emb(const float* __restrict__ emb, char* __restrict__ ws,
                         float* __restrict__ out) {
    int gt = blockIdx.x * 256 + threadIdx.x;        // 64 blocks -> 0..16383
    if (gt == 0) out[OUT_LOSS] = 0.f;
    if (gt < 256) out[OUT_SUM + gt] = 0.f;
    {   // embedding passthrough (OUT_EMB odd offset -> scalar stores)
        float4 v = *(const float4*)(emb + (size_t)gt * 4);
        float* o = out + OUT_EMB + (size_t)gt * 4;
        o[0] = v.x; o[1] = v.y; o[2] = v.z; o[3] = v.w;
    }
    if (gt < 8192) {                                 // one (code, 8-ch octet) each
        int k = gt >> 3, oct = gt & 7;
        int set = k >> 4, row = k & 15;
        int s = oct >> 2, g = oct & 3;               // c = s*32 + g*8 + i
        const float* e = emb + (size_t)k * CDIM + oct * 8;
        char* rec = ws + (size_t)set * SETB;
        // A-frag (16x16x32): lane l = g*16+row holds 8 f16 at chunk + l*16
        _Float16* hi = (_Float16*)(rec + s * 1024 + ((g << 4) | row) * 16);
        _Float16* lo = (_Float16*)(rec + 2048 + s * 1024 + ((g << 4) | row) * 16);
        float s2 = 0.f;
        half8 hv, lv;
#pragma unroll
        for (int i = 0; i < 8; ++i) {
            float v = e[i];
            s2 = fmaf(v, v, s2);
            _Float16 h = (_Float16)v;
            hv[i] = h;
            lv[i] = (_Float16)(v - (float)h);
        }
        *(half8*)hi = hv;
        *(half8*)lo = lv;
        s2 += __shfl_xor(s2, 1);                     // reduce over the octet group
        s2 += __shfl_xor(s2, 2);
        s2 += __shfl_xor(s2, 4);
        if (oct == 0) ((float*)(ws + EIOFF))[k] = -0.5f * s2;   // eiE[k], k=set*16+g*4+r
    }
}

// async global->LDS, 16B per lane
#define GLDS16(GSRC, LDST)                                                     \
    __builtin_amdgcn_global_load_lds(                                          \
        (const __attribute__((address_space(1))) void*)(GSRC),                 \
        (__attribute__((address_space(3))) void*)(LDST), 16, 0, 0)

// ---- main VQ kernel ----
// Grid 2048 x 256 thr (4 waves), __launch_bounds__(256,6): 85-VGPR cap fits
// the ~70-reg working set while allowing 6 blocks/CU = 24 waves/CU -- the
// first clean config above 16 waves/CU (every 512-thr attempt spilled:
// (512,4)->64-cap R8/R11, (512,8)->32-cap R15).
// Block owns 32 positions. Wave (pg,kh): pg=wv&1 owns 16 positions (B-frags
// = 16 VGPR), kh=wv>>1 scans half the codebook: 32 sets of 16 codes
// (16x16x32 f16 MFMA, fp16 2-way split, 3 terms = 6 MFMA/round, 1 chain).
// Per-kh 2-slot shared ring; R15's correctness-proven drain-free pipeline:
//   STAGE(r+1) -> vmcnt(2) (waits only set r; r+1 stays in flight) ->
//   s_barrier#1 -> consume -> s_barrier#2 (slot reads done before overwrite).
// Score = x.e - 0.5||e||^2 via MFMA C-init; argmax == argmin distance.
__global__ __launch_bounds__(256, 6) void vq_kernel(
        const float* __restrict__ in, const float* __restrict__ emb,
        const char* __restrict__ wsA, float* __restrict__ out) {
    __shared__ __align__(16) char ring[2][2][SETB];  // [kh][slot] 16KB; xl aliases
    __shared__ __align__(16) float eiL[KCODES];      // 4KB (-0.5||e||^2, idx==k)
    __shared__ float candS[2][BPOS];
    __shared__ int   candK[2][BPOS];
    __shared__ int   kwin[BPOS];
    __shared__ float lred[4];

    const int tid  = threadIdx.x;
    const int lane = tid & 63, wv = tid >> 6;        // 4 waves
    const int col  = lane & 15, g = lane >> 4;       // C col / row-group
    const int pg   = wv & 1, kh = wv >> 1;           // pos-group / codebook half
    const int p0   = blockIdx.x * BPOS;
    const int b    = p0 >> 15;                       // 32-tile never straddles batch
    const int s0   = p0 & 32767;
    const float* xin = in + (size_t)b * (CDIM * SPATIAL) + s0;

    // ---- prologue: x -> xl (aliased on ring), eiL copy ----
    float* xl = (float*)&ring[0][0][0];              // 64 x 33 f32 = 8.4KB <= 16KB
    {
        int p = tid & 31, cq = tid >> 5;             // 8 ch-groups of 8
#pragma unroll
        for (int j = 0; j < 8; ++j) {
            int c = cq * 8 + j;
            xl[c * 33 + p] = xin[(size_t)c * SPATIAL + p];
        }
    }
    *(float4*)&eiL[tid * 4] = *(const float4*)((const float*)(wsA + EIOFF) + tid * 4);
    __syncthreads();

    // ---- B-frags: 16 positions x 64 ch hi/lo = 16 VGPR (R2/R13-verified layout:
    // lane: col=lane&15 (position), k-local = g*8+j within 32-ch half s) ----
    half8 bh[2], bl[2];
#pragma unroll
    for (int s = 0; s < 2; ++s) {
        int pp = pg * 16 + col;
#pragma unroll
        for (int j = 0; j < 8; ++j) {
            int c = s * 32 + g * 8 + j;
            float v = xl[c * 33 + pp];
            _Float16 hh = (_Float16)v;
            bh[s][j] = hh;
            bl[s][j] = (_Float16)(v - (float)hh);
        }
    }
    __syncthreads();                                 // xl dead; ring reusable; vm drained

    // ---- staging: kh-stream = 2 waves (pg 0,1), each stages 2KB of the 4KB set
    const char* myws = wsA + (size_t)kh * NRND * SETB;
#define STAGE(RSET, SLOT) do {                                                 \
        const char* s_ = myws + (size_t)(RSET) * SETB + pg * 2048 + lane * 16; \
        char* d_ = &ring[kh][SLOT][0] + pg * 2048 + lane * 16;                 \
        GLDS16(s_,        d_);                                                 \
        GLDS16(s_ + 1024, d_ + 1024);                                          \
    } while (0)
    STAGE(0, 0);                                     // set 0 in flight

    f32x4 maxS;
    int   maxR[4];
#pragma unroll
    for (int r = 0; r < 4; ++r) { maxS[r] = -3.402823466e38f; maxR[r] = 0; }

    // ---- main loop: 32 rounds, drain-free double-barrier pipeline ----
#pragma unroll 1
    for (int r = 0; r < NRND; ++r) {
        STAGE((r + 1) & (NRND - 1), (r + 1) & 1);    // wrap at tail: harmless
        asm volatile("s_waitcnt vmcnt(2)" ::: "memory");  // own round-r loads done
        __builtin_amdgcn_s_barrier();                // #1: set r valid block-wide
        __builtin_amdgcn_sched_barrier(0);           // fence code motion (rule #18)
        const int set = kh * NRND + r;               // ascending k within stream
        f32x4 eiv = *(const f32x4*)&eiL[set * 16 + g * 4];
        const char* ap = &ring[kh][r & 1][0] + (size_t)lane * 16;
        half8 ah0 = *(const half8*)(ap);
        half8 ah1 = *(const half8*)(ap + 1024);
        half8 al0 = *(const half8*)(ap + 2048);
        half8 al1 = *(const half8*)(ap + 3072);
        // single 6-chain (16 pos tile), ei as C-init
        f32x4 a0 = __builtin_amdgcn_mfma_f32_16x16x32_f16(ah0, bh[0], eiv, 0, 0, 0);
        a0 = __builtin_amdgcn_mfma_f32_16x16x32_f16(ah1, bh[1], a0, 0, 0, 0);
        a0 = __builtin_amdgcn_mfma_f32_16x16x32_f16(ah0, bl[0], a0, 0, 0, 0);
        a0 = __builtin_amdgcn_mfma_f32_16x16x32_f16(ah1, bl[1], a0, 0, 0, 0);
        a0 = __builtin_amdgcn_mfma_f32_16x16x32_f16(al0, bh[0], a0, 0, 0, 0);
        a0 = __builtin_amdgcn_mfma_f32_16x16x32_f16(al1, bh[1], a0, 0, 0, 0);
        // vectorized per-r-slot argmax; sets ascend -> strict > keeps smallest k
#pragma unroll
        for (int rr = 0; rr < 4; ++rr)
            if (a0[rr] > maxS[rr]) { maxS[rr] = a0[rr]; maxR[rr] = set; }
        __builtin_amdgcn_s_barrier();                // #2: slot r&1 reads consumed
    }
#undef STAGE

    // ---- per-lane lex fold (score desc, k asc), cross-g butterfly, publish ----
    {
        float bs = maxS[0];
        int   bk = maxR[0] * 16 + g * 4;
#pragma unroll
        for (int rr = 1; rr < 4; ++rr) {
            float sc = maxS[rr];
            int   kk = maxR[rr] * 16 + g * 4 + rr;
            if (sc > bs || (sc == bs && kk < bk)) { bs = sc; bk = kk; }
        }
#pragma unroll
        for (int m = 16; m <= 32; m <<= 1) {         // combine the 4 row-groups
            float os = __shfl_xor(bs, m);
            int   ok = __shfl_xor(bk, m);
            if (os > bs || (os == bs && ok < bk)) { bs = os; bk = ok; }
        }
        if (g == 0) {
            candS[kh][pg * 16 + col] = bs;
            candK[kh][pg * 16 + col] = bk;
        }
    }
    __syncthreads();

    // ---- combine the two codebook halves (kh ascending -> lex), write indices ----
    if (tid < BPOS) {
        float s0v = candS[0][tid], s1v = candS[1][tid];
        int   k0v = candK[0][tid], k1v = candK[1][tid];
        int sel = (s1v > s0v) || (s1v == s0v && k1v < k0v);
        int bkf = sel ? k1v : k0v;
        kwin[tid] = bkf;
        out[OUT_IDX + p0 + tid] = (float)bkf;
    }
    __syncthreads();

    // ---- epilogue: coalesced q stores, exact f32 x re-read (L2/L3-hot), loss ----
    float lsum = 0.f;
    {
        int p = tid & 31, cq = tid >> 5;
        int kk = kwin[p];
        const float* eb = emb + (size_t)kk * CDIM;
        float* q = out + OUT_Q + (size_t)b * (CDIM * SPATIAL) + s0;
#pragma unroll
        for (int j = 0; j < 8; ++j) {
            int c = cq * 8 + j;
            float x = xin[(size_t)c * SPATIAL + p];
            float e = eb[c];
            float d = e - x;                         // stop_grad(q - x)
            lsum = fmaf(d, d, lsum);
            q[(size_t)c * SPATIAL + p] = x + d;      // straight-through
        }
    }
#pragma unroll
    for (int off = 32; off > 0; off >>= 1) lsum += __shfl_down(lsum, off);
    if (lane == 0) lred[wv] = lsum;
    __syncthreads();
    if (tid == 0) {
        float t = lred[0] + lred[1] + lred[2] + lred[3];
        atomicAdd(out + OUT_LOSS, t * (0.25f / (float)NEL));
    }
}

extern "C" void kernel_launch(void* const* d_in, const int* in_sizes, int n_in,
                              void* d_out, int out_size, void* d_ws, size_t ws_size,
                              hipStream_t stream) {
    const float* in  = (const float*)d_in[0];   // [2,64,32,32,32] f32
    const float* emb = (const float*)d_in[1];   // [1024,64] f32
    float* out = (float*)d_out;
    char*  ws  = (char*)d_ws;                   // 266,240 B used

    prep_emb<<<64, 256, 0, stream>>>(emb, ws, out);
    vq_kernel<<<NPOS / BPOS, 256, 0, stream>>>(in, emb, ws, out);
}

// Round 18
// 41.793 us; speedup vs baseline: 1.4642x; 1.4642x over previous
//
#include <hip/hip_runtime.h>
#include <stdint.h>

#define KCODES  1024
#define CDIM    64
#define SPATIAL 32768
#define NPOS    65536
#define NEL     4194304

// d_out layout (floats), outputs concatenated in reference return order
#define OUT_Q    0
#define OUT_LOSS 4194304
#define OUT_IDX  4194305
#define OUT_SUM  4259841
#define OUT_EMB  4260097

// ws: 32 sets x 8KB {Ah0,Al0,Ah1,Al1,Ah2,Al2,Ah3,Al3} (1KB chunks, lane-linear),
// then eiExp[32][2][16] f32 at EIEXP: per-lane C-init vectors (-0.5*||e||^2)
#define NSET  32
#define SETB  8192
#define EIEXP 262144
#define BPOS  128
#define NRND  16           // rounds per wave (K-split 2: 16 sets each)

typedef _Float16 half8  __attribute__((ext_vector_type(8)));
typedef float    f32x4  __attribute__((ext_vector_type(4)));
typedef float    f32x16 __attribute__((ext_vector_type(16)));

// ---- prep: fragment-swizzle codebook (32x32x16 A-frags), eiExp, zero, passthrough ----
__global__ void prep_emb(const float* __restrict__ emb, char* __restrict__ ws,
                         float* __restrict__ out) {
    int gt = blockIdx.x * 256 + threadIdx.x;        // 64 blocks -> 0..16383
    if (gt == 0) out[OUT_LOSS] = 0.f;
    if (gt < 256) out[OUT_SUM + gt] = 0.f;
    {   // embedding passthrough (OUT_EMB odd offset -> scalar stores)
        float4 v = *(const float4*)(emb + (size_t)gt * 4);
        float* o = out + OUT_EMB + (size_t)gt * 4;
        o[0] = v.x; o[1] = v.y; o[2] = v.z; o[3] = v.w;
    }
    if (gt < 8192) {                                 // one (code, 8-ch octet) each
        int k = gt >> 3, oct = gt & 7;
        int set = k >> 5, row = k & 31;
        int ks = oct >> 1, hc = oct & 1;             // c = ks*16 + hc*8 + i
        const float* e = emb + (size_t)k * CDIM + oct * 8;
        char* rec = ws + (size_t)set * SETB;
        // A-frag: lane l = hc*32+row holds 8 fp16 at chunk(ks,hi/lo) + l*16
        _Float16* hi = (_Float16*)(rec + (ks * 2 + 0) * 1024 + (hc * 32 + row) * 16);
        _Float16* lo = (_Float16*)(rec + (ks * 2 + 1) * 1024 + (hc * 32 + row) * 16);
        float s2 = 0.f;
        half8 hv, lv;
#pragma unroll
        for (int i = 0; i < 8; ++i) {
            float v = e[i];
            s2 = fmaf(v, v, s2);
            _Float16 h = (_Float16)v;
            hv[i] = h;
            lv[i] = (_Float16)(v - (float)h);
        }
        *(half8*)hi = hv;
        *(half8*)lo = lv;
        s2 += __shfl_xor(s2, 1);                     // reduce over the octet group
        s2 += __shfl_xor(s2, 2);
        s2 += __shfl_xor(s2, 4);
        if (oct == 0) {
            // C/D row = (q&3) + 8*(q>>2) + 4h  ->  h = bit2(row), q = (row&3)|((row>>3)<<2)
            int hh = (row >> 2) & 1;
            int q  = (row & 3) | ((row >> 3) << 2);
            ((float*)(ws + EIEXP))[(set * 2 + hh) * 16 + q] = -0.5f * s2;
        }
    }
}

// async global->LDS, 16B per lane
#define GLDS16(GSRC, LDST)                                                     \
    __builtin_amdgcn_global_load_lds(                                          \
        (const __attribute__((address_space(1))) void*)(GSRC),                 \
        (__attribute__((address_space(3))) void*)(LDST), 16, 0, 0)

// ---- main VQ kernel ----
// R10's session-best geometry + two proven fixes:
//  (a) __launch_bounds__(512,2): single-chain working set (~75-90 regs)
//      allocates CLEAN (R10 ran under (512,4)'s 64-cap -> likely hidden spill).
//  (b) drain-free pipeline: per-round vmcnt(2) + RAW s_barrier (+sched_barrier)
//      instead of __syncthreads (which compiles to a vmcnt(0) lgkmcnt(0) drain
//      -- the m97 ~20% stall). 3-slot ring => WAR distance = 1 round + barrier
//      (race-free; discipline validated on HW in R17).
// Grid 512 x 512 thr (8 waves) = 2 blocks/CU (LDS ~55KB). Block owns 128 pos.
// Wave (pg,kh): pg=wv&3 owns 32 positions, kh=wv>>2 scans half the codebook
// (16 sets of 32 codes; 12 x mfma_32x32x16 single chain, fp16 2-way split).
// Score = x.e - 0.5||e||^2 via MFMA C-init; argmax == argmin distance.
__global__ __launch_bounds__(512, 2) void vq_kernel(
        const float* __restrict__ in, const float* __restrict__ emb,
        const char* __restrict__ wsA, float* __restrict__ out) {
    // ring[kh][slot] : 6 x 8KB = 48KB; xl (33KB) aliases onto it
    __shared__ __align__(16) char ring[6][SETB];
    __shared__ __align__(16) float eiL[NSET * 32];   // 4KB C-init vectors
    __shared__ float candS[2][BPOS];
    __shared__ int   candK[2][BPOS];
    __shared__ int   kwin[BPOS];
    __shared__ float lred[8];

    const int tid  = threadIdx.x;
    const int lane = tid & 63, wv = tid >> 6;        // 8 waves
    const int col  = lane & 31, h = lane >> 5;
    const int pg   = wv & 3, kh = wv >> 2;           // pos-group / K-half
    const int p0   = blockIdx.x * BPOS;
    const int b    = p0 >> 15;                       // 128-tile never straddles batch
    const int s0   = p0 & 32767;
    const float* xin = in + (size_t)b * (CDIM * SPATIAL) + s0;
    const float* eiG = (const float*)(wsA + EIEXP);

    // ---- prologue: x -> xl (aliased), B-frags, eiL ----
    float* xl = (float*)&ring[0][0];                 // 64 x 129 floats = 33KB
    {
        int p = tid & 127, cq = tid >> 7;
#pragma unroll
        for (int j = 0; j < 16; ++j) {
            int c = cq * 16 + j;
            xl[c * 129 + p] = xin[(size_t)c * SPATIAL + p];
        }
    }
    eiL[tid] = eiG[tid];
    eiL[tid + 512] = eiG[tid + 512];
    __syncthreads();

    half8 bh[4], bl[4];                              // 32 pos x 64 ch hi/lo = 32 VGPR
    {
        int pp = pg * 32 + col;
#pragma unroll
        for (int ks = 0; ks < 4; ++ks)
#pragma unroll
            for (int j = 0; j < 8; ++j) {
                int c = ks * 16 + h * 8 + j;         // B k-local = h*8+j (matches A)
                float v = xl[c * 129 + pp];
                _Float16 hh = (_Float16)v;
                bh[ks][j] = hh;
                bl[ks][j] = (_Float16)(v - (float)hh);
            }
    }
    __syncthreads();                                 // xl dead; ring reusable; vm drained

    // pre-stage rounds 0,1 of own stream (wave stages its pg's 2KB quarter)
    char* sl0 = &ring[kh * 3 + 0][0];
    char* sl1 = &ring[kh * 3 + 1][0];
    char* sl2 = &ring[kh * 3 + 2][0];
#define STAGE2(RSET, DST) do {                                                 \
        const char* src_ = wsA + (size_t)(RSET) * SETB + pg * 2048 + lane * 16;\
        char* dst_ = (DST) + pg * 2048 + lane * 16;                            \
        GLDS16(src_, dst_);                                                    \
        GLDS16(src_ + 1024, dst_ + 1024);                                      \
    } while (0)
    STAGE2(kh * 16 + 0, sl0);
    STAGE2(kh * 16 + 1, sl1);
    asm volatile("s_waitcnt vmcnt(2)" ::: "memory"); // round-0 data drained
    __builtin_amdgcn_s_barrier();                    // raw: round-1 stays in flight
    __builtin_amdgcn_sched_barrier(0);

    // ---- main loop: 16 rounds, 3-slot ring, stage 2 ahead, DRAIN-FREE ----
    f32x16 maxS;
    int    maxR[16];
#pragma unroll
    for (int q = 0; q < 16; ++q) { maxS[q] = -3.402823466e38f; maxR[q] = 0; }

#pragma unroll 1
    for (int r = 0; r < NRND; ++r) {
        STAGE2(kh * 16 + ((r + 2) & 15), sl2);       // wraps at tail: harmless
        const int setid = kh * 16 + r;
        f32x16 eiv = *(const f32x16*)&eiL[(setid * 2 + h) * 16];
        const char* ap = sl0 + (size_t)lane * 16;
        f32x16 a;
        {
            half8 ah0 = *(const half8*)(ap);
            half8 al0 = *(const half8*)(ap + 1024);
            half8 ah1 = *(const half8*)(ap + 2048);
            half8 al1 = *(const half8*)(ap + 3072);
            half8 ah2 = *(const half8*)(ap + 4096);
            half8 al2 = *(const half8*)(ap + 5120);
            half8 ah3 = *(const half8*)(ap + 6144);
            half8 al3 = *(const half8*)(ap + 7168);
            a = __builtin_amdgcn_mfma_f32_32x32x16_f16(ah0, bh[0], eiv, 0, 0, 0);
            a = __builtin_amdgcn_mfma_f32_32x32x16_f16(ah0, bl[0], a, 0, 0, 0);
            a = __builtin_amdgcn_mfma_f32_32x32x16_f16(al0, bh[0], a, 0, 0, 0);
            a = __builtin_amdgcn_mfma_f32_32x32x16_f16(ah1, bh[1], a, 0, 0, 0);
            a = __builtin_amdgcn_mfma_f32_32x32x16_f16(ah1, bl[1], a, 0, 0, 0);
            a = __builtin_amdgcn_mfma_f32_32x32x16_f16(al1, bh[1], a, 0, 0, 0);
            a = __builtin_amdgcn_mfma_f32_32x32x16_f16(ah2, bh[2], a, 0, 0, 0);
            a = __builtin_amdgcn_mfma_f32_32x32x16_f16(ah2, bl[2], a, 0, 0, 0);
            a = __builtin_amdgcn_mfma_f32_32x32x16_f16(al2, bh[2], a, 0, 0, 0);
            a = __builtin_amdgcn_mfma_f32_32x32x16_f16(ah3, bh[3], a, 0, 0, 0);
            a = __builtin_amdgcn_mfma_f32_32x32x16_f16(ah3, bl[3], a, 0, 0, 0);
            a = __builtin_amdgcn_mfma_f32_32x32x16_f16(al3, bh[3], a, 0, 0, 0);
        }
        // vectorized per-q-slot argmax: 16 independent states, no serial chain.
        // For fixed q, k grows with r -> strict > keeps smallest k.
#pragma unroll
        for (int q = 0; q < 16; ++q)
            if (a[q] > maxS[q]) { maxS[q] = a[q]; maxR[q] = setid; }
        char* t0 = sl0; sl0 = sl1; sl1 = sl2; sl2 = t0;   // rotate ring
        asm volatile("s_waitcnt vmcnt(2)" ::: "memory");  // next round's set done;
                                                          // round r+2 stays in flight
        __builtin_amdgcn_s_barrier();                     // raw, no drain
        __builtin_amdgcn_sched_barrier(0);                // pin consume below barrier
    }
#undef STAGE2

    // ---- per-lane lex fold over q-slots (score desc, k asc) ----
    float best = maxS[0];
    int   bk   = maxR[0] * 32 + 4 * h;
#pragma unroll
    for (int q = 1; q < 16; ++q) {
        float sc = maxS[q];
        int   kk = maxR[q] * 32 + 4 * h + (q & 3) + 8 * (q >> 2);
        if (sc > best || (sc == best && kk < bk)) { best = sc; bk = kk; }
    }
    // cross-h combine (same position, disjoint code rows)
    {
        float os = __shfl_xor(best, 32);
        int   ok = __shfl_xor(bk, 32);
        if (os > best || (os == best && ok < bk)) { best = os; bk = ok; }
    }
    if (h == 0) {
        candS[kh][pg * 32 + col] = best;
        candK[kh][pg * 32 + col] = bk;
    }
    __syncthreads();

    // ---- combine the two K-halves, write indices ----
    if (tid < BPOS) {
        float s0v = candS[0][tid], s1v = candS[1][tid];
        int   k0v = candK[0][tid], k1v = candK[1][tid];
        int sel = (s1v > s0v) || (s1v == s0v && k1v < k0v);
        int bkf = sel ? k1v : k0v;
        kwin[tid] = bkf;
        out[OUT_IDX + p0 + tid] = (float)bkf;
    }
    __syncthreads();

    // ---- epilogue: coalesced q stores, exact f32 x re-read (L2-hot), loss ----
    float lsum = 0.f;
    {
        int p = tid & 127, cq = tid >> 7;
        int kk = kwin[p];
        const float* eb = emb + (size_t)kk * CDIM;
        float* q = out + OUT_Q + (size_t)b * (CDIM * SPATIAL) + s0;
#pragma unroll
        for (int j = 0; j < 16; ++j) {
            int c = cq * 16 + j;
            float x = xin[(size_t)c * SPATIAL + p];
            float e = eb[c];
            float d = e - x;                         // stop_grad(q - x)
            lsum = fmaf(d, d, lsum);
            q[(size_t)c * SPATIAL + p] = x + d;      // straight-through
        }
    }
#pragma unroll
    for (int off = 32; off > 0; off >>= 1) lsum += __shfl_down(lsum, off);
    if (lane == 0) lred[wv] = lsum;
    __syncthreads();
    if (tid == 0) {
        float t = 0.f;
#pragma unroll
        for (int w = 0; w < 8; ++w) t += lred[w];
        atomicAdd(out + OUT_LOSS, t * (0.25f / (float)NEL));
    }
}

extern "C" void kernel_launch(void* const* d_in, const int* in_sizes, int n_in,
                              void* d_out, int out_size, void* d_ws, size_t ws_size,
                              hipStream_t stream) {
    const float* in  = (const float*)d_in[0];   // [2,64,32,32,32] f32
    const float* emb = (const float*)d_in[1];   // [1024,64] f32
    float* out = (float*)d_out;
    char*  ws  = (char*)d_ws;                   // 266,240 B used

    prep_emb<<<64, 256, 0, stream>>>(emb, ws, out);
    vq_kernel<<<NPOS / BPOS, 512, 0, stream>>>(in, emb, ws, out);
}